// Round 5
// baseline (468.670 us; speedup 1.0000x reference)
//
#include <hip/hip_runtime.h>
#include <hip/hip_bf16.h>
#include <stdint.h>

// VQ-VAE vector quantizer for MI355X (gfx950)
// z: [32768,256] f32, codebook: [256,8192] f32
// out: z_q [8388608] f32, indices-as-f32 [32768], loss [1]
//
// Round 5: re-tiled scan. 256-thread blocks, 64 rows x all codes; per
// 256-code tile the 4 waves own DISJOINT 64-code groups -> every B granule
// is loaded exactly once per block (round 4 loaded each twice), straight
// global->register, no main-loop barriers. acc 64 regs/wave -> 3 blocks/CU
// (12 waves, was 8). z staged once in 32KB LDS (proven swizzle). Scores
// bitwise-identical to rounds 1/3/4; bucket structure still 64 buckets x
// top-2 + exact fp64 top-5 refine. Two half-dispatches + exact merge.

#define DEVINL __device__ __forceinline__

typedef float f32x4 __attribute__((ext_vector_type(4)));
typedef short short8 __attribute__((ext_vector_type(8)));

#define NROWS   32768
#define DIMS    256
#define NCODES  8192
#define KMIN    ((int)0x80000000)

// ---------------- helpers ----------------
DEVINL unsigned pkbf(float x, float y) {
  unsigned a = __float_as_uint(x); a = (a + 0x7fffu + ((a >> 16) & 1u)) >> 16;
  unsigned b = __float_as_uint(y); b = (b + 0x7fffu + ((b >> 16) & 1u)) >> 16;
  return a | (b << 16);
}

// ---------------- K1: column norms ----------------
__global__ void k_colnorm(const float* __restrict__ cb, float* __restrict__ cn) {
  __shared__ float p[256];
  int j = blockIdx.x * 32 + (threadIdx.x & 31);
  int seg = threadIdx.x >> 5;
  float s = 0.f;
  for (int i = 0; i < 32; ++i) {
    float v = cb[(size_t)(seg * 32 + i) * NCODES + j];
    s = fmaf(v, v, s);
  }
  p[threadIdx.x] = s;
  __syncthreads();
  if (threadIdx.x < 32) {
    float t = 0.f;
    for (int k = 0; k < 8; ++k) t += p[k * 32 + threadIdx.x];
    cn[j] = 0.5f * t;
  }
}

// ---------------- K2: f32 transpose cbTf[j][d] ----------------
__global__ void k_transpose(const float* __restrict__ cb, float* __restrict__ cbTf) {
  __shared__ float t[64][65];
  int j0 = blockIdx.x * 64, d0 = blockIdx.y * 64;
  int tx = threadIdx.x & 63, ty = threadIdx.x >> 6;
  #pragma unroll
  for (int i = 0; i < 16; ++i) {
    int dl = i * 4 + ty;
    t[dl][tx] = cb[(size_t)(d0 + dl) * NCODES + j0 + tx];
  }
  __syncthreads();
  #pragma unroll
  for (int i = 0; i < 16; ++i) {
    int jl = i * 4 + ty;
    cbTf[(size_t)(j0 + jl) * DIMS + d0 + tx] = t[tx][jl];
  }
}

// ---------------- K3: bf16 fragment image ----------------
// granule g (16B) = [step 256][w 4][cf 4][lgr 4][l15 16]
//   step = tile*8+chunk (tile of 256 codes, chunk = BK32 of dims)
//   code j = tile*256 + w*64 + cf*16 + l15;  dims d = chunk*32 + lgr*8 .. +8
// scan: wave w at step reads granule step*1024 + w*256 + cf*64 + lane (linear)
__global__ void k_image(const float* __restrict__ cbTf, uint4* __restrict__ img) {
  int g = blockIdx.x * 256 + threadIdx.x;     // 0..262143
  int step = g >> 10;                          // 0..255
  int r = g & 1023;
  int w = r >> 8, cf = (r >> 6) & 3, lgr = (r >> 4) & 3, l15 = r & 15;
  int tile = step >> 3, chunk = step & 7;
  int j = tile * 256 + w * 64 + cf * 16 + l15;
  int d = chunk * 32 + lgr * 8;
  const float4* s4 = (const float4*)(cbTf + (size_t)j * DIMS + d);
  float4 u = s4[0], v = s4[1];
  uint4 o;
  o.x = pkbf(u.x, u.y); o.y = pkbf(u.z, u.w);
  o.z = pkbf(v.x, v.y); o.w = pkbf(v.z, v.w);
  img[g] = o;
}

// ---------------- K4: MFMA scan over one code half ----------------
// 512 blocks x 256 threads. Block: 64 rows x 4096 codes (tiles tile0..+16).
// 4 waves each own a disjoint 64-code group per 256-code tile; wave-tile
// 64 rows x 64 codes (rf4 x cf4, 16x16x32). B global->reg double-buffered,
// one step ahead; A from 32KB LDS z-tile; no barriers in the main loop.
// merge!=0: fold previously-written cand top-2 in before writing (exact).
__global__ __launch_bounds__(256, 3)
void k_scan(const float* __restrict__ z, const float* __restrict__ cn,
            const short8* __restrict__ img, int2* __restrict__ cand,
            int tile0, int merge) {
  __shared__ char smem[32768];                // z: 64 rows x 512B, XOR-swizzled
  const int t = threadIdx.x;
  const int lane = t & 63;
  const int wave = t >> 6;                    // code group 0..3
  const int l15 = lane & 15;
  const int lgr = lane >> 4;
  const int brow = blockIdx.x * 64;

  // stage z: f32 -> bf16, granule (16B) position = (col16 ^ (row&31))
  #pragma unroll
  for (int i = 0; i < 16; ++i) {
    int g = t + i * 256;
    int row = g >> 6, col = g & 63;
    float4 v = *(const float4*)(z + (size_t)(brow + row) * DIMS + col * 4);
    unsigned lo = pkbf(v.x, v.y), hi = pkbf(v.z, v.w);
    int addr = row * 512 + ((col * 8) ^ ((row & 31) << 4));
    *(uint2*)(smem + addr) = make_uint2(lo, hi);
  }

  // per row-slot top-2 packed keys
  int k1[16], k2[16];
  #pragma unroll
  for (int i = 0; i < 16; ++i) { k1[i] = KMIN; k2[i] = KMIN; }

  // B prefetch: first step of this half into b0
  const short8* bp = img + (size_t)(tile0 * 8) * 1024 + wave * 256 + lane;
  short8 b0[4], b1[4];
  #pragma unroll
  for (int cf = 0; cf < 4; ++cf) b0[cf] = bp[cf * 64];
  bp += 1024;

  __syncthreads();

  f32x4 acc[4][4];

  #pragma unroll 1
  for (int tt = 0; tt < 16; ++tt) {
    const int tile = tile0 + tt;
    // acc init: -0.5*||c||^2
    #pragma unroll
    for (int cf = 0; cf < 4; ++cf) {
      float h = -cn[tile * 256 + wave * 64 + cf * 16 + l15];
      #pragma unroll
      for (int rf = 0; rf < 4; ++rf) acc[rf][cf] = f32x4{h, h, h, h};
    }
    #pragma unroll
    for (int cp = 0; cp < 4; ++cp) {
      // ---- even chunk: prefetch->b1, consume b0 ----
      #pragma unroll
      for (int cf = 0; cf < 4; ++cf) b1[cf] = bp[cf * 64];
      bp += 1024;
      {
        const int chunk = cp * 2;
        short8 a[4];
        #pragma unroll
        for (int rf = 0; rf < 4; ++rf) {
          int m = rf * 16 + l15;
          int by = ((chunk * 4 + lgr) ^ (m & 31)) << 4;
          a[rf] = *(const short8*)(smem + m * 512 + by);
        }
        #pragma unroll
        for (int rf = 0; rf < 4; ++rf)
          #pragma unroll
          for (int cf = 0; cf < 4; ++cf)
            acc[rf][cf] = __builtin_amdgcn_mfma_f32_16x16x32_bf16(a[rf], b0[cf], acc[rf][cf], 0, 0, 0);
      }
      // ---- odd chunk: prefetch->b0, consume b1 ----
      #pragma unroll
      for (int cf = 0; cf < 4; ++cf) b0[cf] = bp[cf * 64];
      bp += 1024;
      {
        const int chunk = cp * 2 + 1;
        short8 a[4];
        #pragma unroll
        for (int rf = 0; rf < 4; ++rf) {
          int m = rf * 16 + l15;
          int by = ((chunk * 4 + lgr) ^ (m & 31)) << 4;
          a[rf] = *(const short8*)(smem + m * 512 + by);
        }
        #pragma unroll
        for (int rf = 0; rf < 4; ++rf)
          #pragma unroll
          for (int cf = 0; cf < 4; ++cf)
            acc[rf][cf] = __builtin_amdgcn_mfma_f32_16x16x32_bf16(a[rf], b1[cf], acc[rf][cf], 0, 0, 0);
      }
    }
    // epilogue: fold 4 scores/row-slot into running top-2 (proven exact ops)
    {
      const int jinvb = 8191 - (tile * 256 + wave * 64 + l15);
      #pragma unroll
      for (int rf = 0; rf < 4; ++rf)
        #pragma unroll
        for (int cf = 0; cf < 4; ++cf) {
          int jinv = jinvb - cf * 16;
          #pragma unroll
          for (int r = 0; r < 4; ++r) {
            int si = rf * 4 + r;
            int iq = (int)(acc[rf][cf][r] * 256.0f);
            int k = iq * 8192 + jinv;
            int t1 = max(k1[si], k);
            int t2 = min(k1[si], k);
            k1[si] = t1;
            k2[si] = max(k2[si], t2);
          }
        }
    }
  }

  // write candidates: [row][64 buckets] int2; merge pass folds prior half in
  #pragma unroll
  for (int rf = 0; rf < 4; ++rf)
    #pragma unroll
    for (int r = 0; r < 4; ++r) {
      int row = brow + rf * 16 + lgr * 4 + r;
      int si = rf * 4 + r;
      size_t ci = (size_t)row * 64 + wave * 16 + l15;
      int a1 = k1[si], a2 = k2[si];
      if (merge) {
        int2 old = cand[ci];
        int t1 = max(a1, old.x), t2 = min(a1, old.x);
        a1 = t1; a2 = max(a2, t2);
        t1 = max(a1, old.y); t2 = min(a1, old.y);
        a1 = t1; a2 = max(a2, t2);
      }
      cand[ci] = make_int2(a1, a2);
    }
}

// ---------------- K5: exact fp64 refine (top-5) + outputs + loss partials ----
__global__ __launch_bounds__(512)
void k_refine(const float* __restrict__ z, const float* __restrict__ cbTf,
              const int2* __restrict__ cand, float* __restrict__ zq,
              float* __restrict__ oidx, double* __restrict__ parts) {
  __shared__ double lsum[8];
  int lane = threadIdx.x & 63, wave = threadIdx.x >> 6;
  int row = blockIdx.x * 8 + wave;

  float4 z4 = ((const float4*)(z + (size_t)row * DIMS))[lane];
  int2 kp = cand[(size_t)row * 64 + lane];
  int ka = kp.x, kb = kp.y;

  double bd = 1e300; int bj = -1; float4 bc = {0.f, 0.f, 0.f, 0.f};
  for (int s = 0; s < 5; ++s) {
    int km = max(ka, kb);
    #pragma unroll
    for (int m = 1; m < 64; m <<= 1) km = max(km, __shfl_xor(km, m, 64));
    int j = 8191 - (km & 8191);
    if (ka == km) ka = KMIN; else if (kb == km) kb = KMIN;

    float4 c4 = ((const float4*)(cbTf + (size_t)j * DIMS))[lane];
    double dx = (double)z4.x - (double)c4.x;
    double dy = (double)z4.y - (double)c4.y;
    double dzv = (double)z4.z - (double)c4.z;
    double dw = (double)z4.w - (double)c4.w;
    double d = dx * dx + dy * dy + dzv * dzv + dw * dw;
    #pragma unroll
    for (int m = 1; m < 64; m <<= 1) d += __shfl_xor(d, m, 64);

    bool bt = (d < bd) || (d == bd && j < bj);   // wave-uniform
    if (bt) { bd = d; bj = j; bc = c4; }
  }

  ((float4*)(zq + (size_t)row * DIMS))[lane] = bc;
  if (lane == 0) oidx[row] = (float)bj;

  double lx = (double)bc.x - (double)z4.x;
  double ly = (double)bc.y - (double)z4.y;
  double lz = (double)bc.z - (double)z4.z;
  double lw = (double)bc.w - (double)z4.w;
  double l = lx * lx + ly * ly + lz * lz + lw * lw;
  #pragma unroll
  for (int m = 1; m < 64; m <<= 1) l += __shfl_xor(l, m, 64);
  if (lane == 0) lsum[wave] = l;
  __syncthreads();
  if (threadIdx.x == 0) {
    double s = 0;
    for (int i = 0; i < 8; ++i) s += lsum[i];
    parts[blockIdx.x] = s;
  }
}

// ---------------- K6: loss finalize ----------------
__global__ void k_finish(const double* __restrict__ parts, float* __restrict__ out) {
  __shared__ double s[256];
  double a = 0;
  for (int i = threadIdx.x; i < 4096; i += 256) a += parts[i];
  s[threadIdx.x] = a;
  __syncthreads();
  for (int w = 128; w; w >>= 1) {
    if (threadIdx.x < w) s[threadIdx.x] += s[threadIdx.x + w];
    __syncthreads();
  }
  if (threadIdx.x == 0) out[0] = (float)(1.25 * s[0] / 8388608.0);
}

// ---------------- launch ----------------
extern "C" void kernel_launch(void* const* d_in, const int* in_sizes, int n_in,
                              void* d_out, int out_size, void* d_ws, size_t ws_size,
                              hipStream_t stream) {
  const float* zin = (const float*)d_in[0];
  const float* cb  = (const float*)d_in[1];
  float* out = (float*)d_out;

  char* w = (char*)d_ws;
  float*  cn    = (float*)w;                                        // 32 KB
  float*  cbTf  = (float*)(w + 32768);                              // 8 MB
  char*   imgb  = w + 32768 + 8388608;                              // 4 MB (+32KB pad)
  int2*   cand  = (int2*)(w + 32768 + 8388608 + 4194304 + 32768);   // 16 MB
  double* parts = (double*)(w + 32768 + 8388608 + 4194304 + 32768 + 16777216); // 32 KB

  float* zq_out   = out;
  float* idx_out  = out + 8388608;
  float* loss_out = out + 8388608 + 32768;

  k_colnorm<<<dim3(256), dim3(256), 0, stream>>>(cb, cn);
  k_transpose<<<dim3(128, 4), dim3(256), 0, stream>>>(cb, cbTf);
  k_image<<<dim3(1024), dim3(256), 0, stream>>>(cbTf, (uint4*)imgb);
  k_scan<<<dim3(512), dim3(256), 0, stream>>>(zin, cn, (const short8*)imgb, cand, 0, 0);
  k_scan<<<dim3(512), dim3(256), 0, stream>>>(zin, cn, (const short8*)imgb, cand, 16, 1);
  k_refine<<<dim3(4096), dim3(512), 0, stream>>>(zin, cbTf, cand, zq_out, idx_out, parts);
  k_finish<<<dim3(1), dim3(256), 0, stream>>>(parts, loss_out);
}

// Round 6
// 208.320 us; speedup vs baseline: 2.2498x; 2.2498x over previous
//
#include <hip/hip_runtime.h>
#include <hip/hip_bf16.h>
#include <stdint.h>

// VQ-VAE vector quantizer for MI355X (gfx950)
// z: [32768,256] f32, codebook: [256,8192] f32
// out: z_q [8388608] f32, indices-as-f32 [32768], loss [1]
//
// Round 6: back to round-1 tiling (128 rows x 8192 codes/block, 8 waves,
// B staged in LDS -> FETCH was 33MB there), with the m97-style staging:
// B via global_load_lds (16B, linear copy, no reg round-trip), fragment-
// linear B layout (stride-1 ds_read_b128, conflict-free), ONE barrier per
// step (next-step loads issued at top, 1241 cyc of MFMA cover, drained by
// __syncthreads' vmcnt(0)), cn cached in LDS. Scores/top-2/fp64-refine
// bitwise identical to passing rounds.

#define DEVINL __device__ __forceinline__

typedef float f32x4 __attribute__((ext_vector_type(4)));
typedef short short8 __attribute__((ext_vector_type(8)));

#define NROWS   32768
#define DIMS    256
#define NCODES  8192
#define KMIN    ((int)0x80000000)

// ---------------- helpers ----------------
DEVINL unsigned pkbf(float x, float y) {
  unsigned a = __float_as_uint(x); a = (a + 0x7fffu + ((a >> 16) & 1u)) >> 16;
  unsigned b = __float_as_uint(y); b = (b + 0x7fffu + ((b >> 16) & 1u)) >> 16;
  return a | (b << 16);
}

DEVINL void gload_lds16(const void* g, void* lds) {
  __builtin_amdgcn_global_load_lds(
      (const __attribute__((address_space(1))) uint32_t*)(uintptr_t)g,
      (__attribute__((address_space(3))) uint32_t*)(uint32_t)(uintptr_t)lds,
      16, 0, 0);
}

// ---------------- K1: column norms ----------------
__global__ void k_colnorm(const float* __restrict__ cb, float* __restrict__ cn) {
  __shared__ float p[256];
  int j = blockIdx.x * 32 + (threadIdx.x & 31);
  int seg = threadIdx.x >> 5;
  float s = 0.f;
  for (int i = 0; i < 32; ++i) {
    float v = cb[(size_t)(seg * 32 + i) * NCODES + j];
    s = fmaf(v, v, s);
  }
  p[threadIdx.x] = s;
  __syncthreads();
  if (threadIdx.x < 32) {
    float t = 0.f;
    for (int k = 0; k < 8; ++k) t += p[k * 32 + threadIdx.x];
    cn[j] = 0.5f * t;
  }
}

// ---------------- K2: f32 transpose cbTf[j][d] ----------------
__global__ void k_transpose(const float* __restrict__ cb, float* __restrict__ cbTf) {
  __shared__ float t[64][65];
  int j0 = blockIdx.x * 64, d0 = blockIdx.y * 64;
  int tx = threadIdx.x & 63, ty = threadIdx.x >> 6;
  #pragma unroll
  for (int i = 0; i < 16; ++i) {
    int dl = i * 4 + ty;
    t[dl][tx] = cb[(size_t)(d0 + dl) * NCODES + j0 + tx];
  }
  __syncthreads();
  #pragma unroll
  for (int i = 0; i < 16; ++i) {
    int jl = i * 4 + ty;
    cbTf[(size_t)(j0 + jl) * DIMS + d0 + tx] = t[tx][jl];
  }
}

// ---------------- K3: bf16 fragment image ----------------
// granule g (16B) = [step 128][wc 4][cf 8][lgr 4][l15 16]
//   step = tile*8+chunk; code j = tile*512 + wc*128 + cf*16 + l15
//   dims d = chunk*32 + lgr*8 .. +8
// LDS B layout is the SAME linear granule order -> staging is a linear copy
// and every b-fragment ds_read_b128 is stride-1 (conflict-free).
__global__ void k_image(const float* __restrict__ cbTf, uint4* __restrict__ img) {
  int g = blockIdx.x * 256 + threadIdx.x;     // 0..262143
  int step = g >> 11;
  int r = g & 2047;
  int wc = r >> 9, cf = (r >> 6) & 7, lgr = (r >> 4) & 3, l15 = r & 15;
  int tile = step >> 3, chunk = step & 7;
  int j = tile * 512 + wc * 128 + cf * 16 + l15;
  int d = chunk * 32 + lgr * 8;
  const float4* s4 = (const float4*)(cbTf + (size_t)j * DIMS + d);
  float4 u = s4[0], v = s4[1];
  uint4 o;
  o.x = pkbf(u.x, u.y); o.y = pkbf(u.z, u.w);
  o.z = pkbf(v.x, v.y); o.w = pkbf(v.z, v.w);
  img[g] = o;
}

// ---------------- K4: MFMA scan, B LDS-staged via global_load_lds ---------
// 256 blocks x 512 threads. Block: 128 rows x 8192 codes.
// Waves: wgr(2) x wc(4); wave-tile 64 rows x 128 codes; 16x16x32 rf4 x cf8.
// LDS: [0,64K) z (XOR-swizzled) | [64K,128K) B double buffer | [128K,160K) cn.
// Per step: issue next chunk's 4 global_load_lds, 32 MFMA cover, one barrier.
__global__ __launch_bounds__(512, 2)
void k_scan(const float* __restrict__ z, const float* __restrict__ cn,
            const uint4* __restrict__ img, int2* __restrict__ cand) {
  __shared__ char smem[163840];
  const int t = threadIdx.x;
  const int lane = t & 63;
  const int wave = t >> 6;
  const int wgr = wave >> 2;
  const int wc  = wave & 3;
  const int l15 = lane & 15;
  const int lgr = lane >> 4;
  const int brow = blockIdx.x * 128;

  char* const zb = smem;                       // 64 KB
  char* const bb = smem + 65536;               // 2 x 32 KB
  const float* const cnl = (const float*)(smem + 131072);  // 32 KB

  // stage z: 128 rows x 256 d f32 -> bf16, granule pos = (col16 ^ (row&31))
  #pragma unroll
  for (int i = 0; i < 16; ++i) {
    int g = t + i * 512;
    int row = g >> 6, col = g & 63;
    float4 v = *(const float4*)(z + (size_t)(brow + row) * DIMS + col * 4);
    unsigned lo = pkbf(v.x, v.y), hi = pkbf(v.z, v.w);
    int addr = row * 512 + ((col * 8) ^ ((row & 31) << 4));
    *(uint2*)(zb + addr) = make_uint2(lo, hi);
  }
  // stage cn: 8192 f32 = 2048 float4 granules, linear
  #pragma unroll
  for (int i = 0; i < 4; ++i) {
    int gidx = t + i * 512;
    ((float4*)(smem + 131072))[gidx] = ((const float4*)cn)[gidx];
  }
  // stage B step 0 into buf0 (granule = i*512 + wave*64 + lane)
  {
    const uint4* gsrc = img + wave * 64 + lane;
    #pragma unroll
    for (int i = 0; i < 4; ++i)
      gload_lds16(gsrc + i * 512, bb + (i * 512 + wave * 64) * 16);
  }

  // per row-slot top-2 packed keys
  int k1[16], k2[16];
  #pragma unroll
  for (int i = 0; i < 16; ++i) { k1[i] = KMIN; k2[i] = KMIN; }

  __syncthreads();   // drains vmcnt(0)+lgkmcnt(0): z, cn, B0 all resident

  f32x4 acc[4][8];

  #pragma unroll 1
  for (int s = 0; s < 128; ++s) {
    const int tile = s >> 3, chunk = s & 7;
    const char* cbuf = bb + (s & 1) * 32768;

    // issue next chunk's staging (lands under this step's MFMA)
    if (s < 127) {
      const uint4* gsrc = img + (size_t)(s + 1) * 2048 + wave * 64 + lane;
      char* dst = bb + ((s + 1) & 1) * 32768;
      #pragma unroll
      for (int i = 0; i < 4; ++i)
        gload_lds16(gsrc + i * 512, dst + (i * 512 + wave * 64) * 16);
    }

    // acc init: -0.5*||c||^2 from LDS cn (broadcast reads, conflict-free)
    if (chunk == 0) {
      #pragma unroll
      for (int cf = 0; cf < 8; ++cf) {
        float h = -cnl[tile * 512 + wc * 128 + cf * 16 + l15];
        #pragma unroll
        for (int rf = 0; rf < 4; ++rf) acc[rf][cf] = f32x4{h, h, h, h};
      }
    }

    // fragments
    short8 a[4], b[8];
    #pragma unroll
    for (int rf = 0; rf < 4; ++rf) {
      int m = wgr * 64 + rf * 16 + l15;
      int by = ((chunk * 4 + lgr) ^ (m & 31)) << 4;
      a[rf] = *(const short8*)(zb + m * 512 + by);
    }
    #pragma unroll
    for (int cf = 0; cf < 8; ++cf)
      b[cf] = *(const short8*)(cbuf + (wc * 512 + cf * 64 + lane) * 16);

    #pragma unroll
    for (int rf = 0; rf < 4; ++rf)
      #pragma unroll
      for (int cf = 0; cf < 8; ++cf)
        acc[rf][cf] = __builtin_amdgcn_mfma_f32_16x16x32_bf16(a[rf], b[cf], acc[rf][cf], 0, 0, 0);

    // tile epilogue: fold 8 scores/row-slot into running top-2 (exact ops)
    if (chunk == 7) {
      const int jinvb = 8191 - (tile * 512 + wc * 128 + l15);
      #pragma unroll
      for (int rf = 0; rf < 4; ++rf)
        #pragma unroll
        for (int cf = 0; cf < 8; ++cf) {
          int jinv = jinvb - cf * 16;
          #pragma unroll
          for (int r = 0; r < 4; ++r) {
            int si = rf * 4 + r;
            int iq = (int)(acc[rf][cf][r] * 256.0f);
            int k = iq * 8192 + jinv;
            int t1 = max(k1[si], k);
            int t2 = min(k1[si], k);
            k1[si] = t1;
            k2[si] = max(k2[si], t2);
          }
        }
    }

    // one barrier per step: its vmcnt(0)+lgkm drain IS the pipeline wait
    __syncthreads();
  }

  // write candidates: [row][64 buckets] int2
  #pragma unroll
  for (int rf = 0; rf < 4; ++rf)
    #pragma unroll
    for (int r = 0; r < 4; ++r) {
      int row = brow + wgr * 64 + rf * 16 + lgr * 4 + r;
      int si = rf * 4 + r;
      cand[(size_t)row * 64 + wc * 16 + l15] = make_int2(k1[si], k2[si]);
    }
}

// ---------------- K5: exact fp64 refine (top-5) + outputs + loss partials ----
__global__ __launch_bounds__(512)
void k_refine(const float* __restrict__ z, const float* __restrict__ cbTf,
              const int2* __restrict__ cand, float* __restrict__ zq,
              float* __restrict__ oidx, double* __restrict__ parts) {
  __shared__ double lsum[8];
  int lane = threadIdx.x & 63, wave = threadIdx.x >> 6;
  int row = blockIdx.x * 8 + wave;

  float4 z4 = ((const float4*)(z + (size_t)row * DIMS))[lane];
  int2 kp = cand[(size_t)row * 64 + lane];
  int ka = kp.x, kb = kp.y;

  double bd = 1e300; int bj = -1; float4 bc = {0.f, 0.f, 0.f, 0.f};
  for (int s = 0; s < 5; ++s) {
    int km = max(ka, kb);
    #pragma unroll
    for (int m = 1; m < 64; m <<= 1) km = max(km, __shfl_xor(km, m, 64));
    int j = 8191 - (km & 8191);
    if (ka == km) ka = KMIN; else if (kb == km) kb = KMIN;

    float4 c4 = ((const float4*)(cbTf + (size_t)j * DIMS))[lane];
    double dx = (double)z4.x - (double)c4.x;
    double dy = (double)z4.y - (double)c4.y;
    double dzv = (double)z4.z - (double)c4.z;
    double dw = (double)z4.w - (double)c4.w;
    double d = dx * dx + dy * dy + dzv * dzv + dw * dw;
    #pragma unroll
    for (int m = 1; m < 64; m <<= 1) d += __shfl_xor(d, m, 64);

    bool bt = (d < bd) || (d == bd && j < bj);   // wave-uniform
    if (bt) { bd = d; bj = j; bc = c4; }
  }

  ((float4*)(zq + (size_t)row * DIMS))[lane] = bc;
  if (lane == 0) oidx[row] = (float)bj;

  double lx = (double)bc.x - (double)z4.x;
  double ly = (double)bc.y - (double)z4.y;
  double lz = (double)bc.z - (double)z4.z;
  double lw = (double)bc.w - (double)z4.w;
  double l = lx * lx + ly * ly + lz * lz + lw * lw;
  #pragma unroll
  for (int m = 1; m < 64; m <<= 1) l += __shfl_xor(l, m, 64);
  if (lane == 0) lsum[wave] = l;
  __syncthreads();
  if (threadIdx.x == 0) {
    double s = 0;
    for (int i = 0; i < 8; ++i) s += lsum[i];
    parts[blockIdx.x] = s;
  }
}

// ---------------- K6: loss finalize ----------------
__global__ void k_finish(const double* __restrict__ parts, float* __restrict__ out) {
  __shared__ double s[256];
  double a = 0;
  for (int i = threadIdx.x; i < 4096; i += 256) a += parts[i];
  s[threadIdx.x] = a;
  __syncthreads();
  for (int w = 128; w; w >>= 1) {
    if (threadIdx.x < w) s[threadIdx.x] += s[threadIdx.x + w];
    __syncthreads();
  }
  if (threadIdx.x == 0) out[0] = (float)(1.25 * s[0] / 8388608.0);
}

// ---------------- launch ----------------
extern "C" void kernel_launch(void* const* d_in, const int* in_sizes, int n_in,
                              void* d_out, int out_size, void* d_ws, size_t ws_size,
                              hipStream_t stream) {
  const float* zin = (const float*)d_in[0];
  const float* cb  = (const float*)d_in[1];
  float* out = (float*)d_out;

  char* w = (char*)d_ws;
  float*  cn    = (float*)w;                                        // 32 KB
  float*  cbTf  = (float*)(w + 32768);                              // 8 MB
  char*   imgb  = w + 32768 + 8388608;                              // 4 MB (+32KB pad)
  int2*   cand  = (int2*)(w + 32768 + 8388608 + 4194304 + 32768);   // 16 MB
  double* parts = (double*)(w + 32768 + 8388608 + 4194304 + 32768 + 16777216); // 32 KB

  float* zq_out   = out;
  float* idx_out  = out + 8388608;
  float* loss_out = out + 8388608 + 32768;

  k_colnorm<<<dim3(256), dim3(256), 0, stream>>>(cb, cn);
  k_transpose<<<dim3(128, 4), dim3(256), 0, stream>>>(cb, cbTf);
  k_image<<<dim3(1024), dim3(256), 0, stream>>>(cbTf, (uint4*)imgb);
  k_scan<<<dim3(256), dim3(512), 0, stream>>>(zin, cn, (const uint4*)imgb, cand);
  k_refine<<<dim3(4096), dim3(512), 0, stream>>>(zin, cbTf, cand, zq_out, idx_out, parts);
  k_finish<<<dim3(1), dim3(256), 0, stream>>>(parts, loss_out);
}

// Round 7
// 205.806 us; speedup vs baseline: 2.2772x; 1.0122x over previous
//
#include <hip/hip_runtime.h>
#include <hip/hip_bf16.h>
#include <stdint.h>

// VQ-VAE vector quantizer for MI355X (gfx950)
// z: [32768,256] f32, codebook: [256,8192] f32
// out: z_q [8388608] f32, indices-as-f32 [32768], loss [1]
//
// Round 7: round-6 structure (128 rows x 8192 codes/block, B staged to LDS
// via global_load_lds, fragment-linear conflict-free layout) with the T4
// counted-vmcnt pipeline: TRIPLE-buffered B (3x32KB), one raw s_barrier per
// step, s_waitcnt vmcnt(4) instead of __syncthreads' full vmcnt(0) drain ->
// next-step loads stay in flight across the barrier. cn back to global
// (L1-resident). Scores/top-2 keys/fp64 top-5 refine bitwise identical to
// the passing rounds.

#define DEVINL __device__ __forceinline__

typedef float f32x4 __attribute__((ext_vector_type(4)));
typedef short short8 __attribute__((ext_vector_type(8)));

#define NROWS   32768
#define DIMS    256
#define NCODES  8192
#define KMIN    ((int)0x80000000)

// ---------------- helpers ----------------
DEVINL unsigned pkbf(float x, float y) {
  unsigned a = __float_as_uint(x); a = (a + 0x7fffu + ((a >> 16) & 1u)) >> 16;
  unsigned b = __float_as_uint(y); b = (b + 0x7fffu + ((b >> 16) & 1u)) >> 16;
  return a | (b << 16);
}

DEVINL void gload_lds16(const void* g, void* lds) {
  __builtin_amdgcn_global_load_lds(
      (const __attribute__((address_space(1))) uint32_t*)(uintptr_t)g,
      (__attribute__((address_space(3))) uint32_t*)(uint32_t)(uintptr_t)lds,
      16, 0, 0);
}

// ---------------- K1: column norms ----------------
__global__ void k_colnorm(const float* __restrict__ cb, float* __restrict__ cn) {
  __shared__ float p[256];
  int j = blockIdx.x * 32 + (threadIdx.x & 31);
  int seg = threadIdx.x >> 5;
  float s = 0.f;
  for (int i = 0; i < 32; ++i) {
    float v = cb[(size_t)(seg * 32 + i) * NCODES + j];
    s = fmaf(v, v, s);
  }
  p[threadIdx.x] = s;
  __syncthreads();
  if (threadIdx.x < 32) {
    float t = 0.f;
    for (int k = 0; k < 8; ++k) t += p[k * 32 + threadIdx.x];
    cn[j] = 0.5f * t;
  }
}

// ---------------- K2: f32 transpose cbTf[j][d] ----------------
__global__ void k_transpose(const float* __restrict__ cb, float* __restrict__ cbTf) {
  __shared__ float t[64][65];
  int j0 = blockIdx.x * 64, d0 = blockIdx.y * 64;
  int tx = threadIdx.x & 63, ty = threadIdx.x >> 6;
  #pragma unroll
  for (int i = 0; i < 16; ++i) {
    int dl = i * 4 + ty;
    t[dl][tx] = cb[(size_t)(d0 + dl) * NCODES + j0 + tx];
  }
  __syncthreads();
  #pragma unroll
  for (int i = 0; i < 16; ++i) {
    int jl = i * 4 + ty;
    cbTf[(size_t)(j0 + jl) * DIMS + d0 + tx] = t[tx][jl];
  }
}

// ---------------- K3: bf16 fragment image ----------------
// granule g (16B) = [step 128][wc 4][cf 8][lgr 4][l15 16]
//   step = tile*8+chunk; code j = tile*512 + wc*128 + cf*16 + l15
//   dims d = chunk*32 + lgr*8 .. +8
// LDS B layout = same linear granule order -> staging is a linear copy and
// every b-fragment ds_read_b128 is stride-1 (conflict-free).
__global__ void k_image(const float* __restrict__ cbTf, uint4* __restrict__ img) {
  int g = blockIdx.x * 256 + threadIdx.x;     // 0..262143
  int step = g >> 11;
  int r = g & 2047;
  int wc = r >> 9, cf = (r >> 6) & 7, lgr = (r >> 4) & 3, l15 = r & 15;
  int tile = step >> 3, chunk = step & 7;
  int j = tile * 512 + wc * 128 + cf * 16 + l15;
  int d = chunk * 32 + lgr * 8;
  const float4* s4 = (const float4*)(cbTf + (size_t)j * DIMS + d);
  float4 u = s4[0], v = s4[1];
  uint4 o;
  o.x = pkbf(u.x, u.y); o.y = pkbf(u.z, u.w);
  o.z = pkbf(v.x, v.y); o.w = pkbf(v.z, v.w);
  img[g] = o;
}

// ---------------- K4: MFMA scan, counted-vmcnt triple-buffer pipeline -----
// 256 blocks x 512 threads. Block: 128 rows x 8192 codes.
// Waves: wgr(2) x wc(4); wave-tile 64 rows x 128 codes; 16x16x32 rf4 x cf8.
// LDS: [0,64K) z (XOR-swizzled) | [64K,160K) B triple buffer (3x32K).
// Step s: issue loads(s+1)->buf[(s+1)%3]; s_waitcnt vmcnt(4); s_barrier;
// compute from buf[s%3]. Loads stay in flight across the barrier (T4).
__global__ __launch_bounds__(512, 2)
void k_scan(const float* __restrict__ z, const float* __restrict__ cn,
            const uint4* __restrict__ img, int2* __restrict__ cand) {
  __shared__ char smem[163840];
  const int t = threadIdx.x;
  const int lane = t & 63;
  const int wave = t >> 6;
  const int wgr = wave >> 2;
  const int wc  = wave & 3;
  const int l15 = lane & 15;
  const int lgr = lane >> 4;
  const int brow = blockIdx.x * 128;

  char* const zb = smem;                       // 64 KB
  char* const bb = smem + 65536;               // 3 x 32 KB

  // stage z: 128 rows x 256 d f32 -> bf16, granule pos = (col16 ^ (row&31))
  #pragma unroll
  for (int i = 0; i < 16; ++i) {
    int g = t + i * 512;
    int row = g >> 6, col = g & 63;
    float4 v = *(const float4*)(z + (size_t)(brow + row) * DIMS + col * 4);
    unsigned lo = pkbf(v.x, v.y), hi = pkbf(v.z, v.w);
    int addr = row * 512 + ((col * 8) ^ ((row & 31) << 4));
    *(uint2*)(zb + addr) = make_uint2(lo, hi);
  }
  // stage B step 0 into buf0 (granule = i*512 + wave*64 + lane)
  {
    const uint4* gsrc = img + wave * 64 + lane;
    #pragma unroll
    for (int i = 0; i < 4; ++i)
      gload_lds16(gsrc + i * 512, bb + (i * 512 + wave * 64) * 16);
  }

  // per row-slot top-2 packed keys
  int k1[16], k2[16];
  #pragma unroll
  for (int i = 0; i < 16; ++i) { k1[i] = KMIN; k2[i] = KMIN; }

  __syncthreads();   // z visible to all waves; step-0 B resident

  f32x4 acc[4][8];
  int b_cur = 0, b_nxt = 1;

  #pragma unroll 1
  for (int s = 0; s < 128; ++s) {
    const int tile = s >> 3, chunk = s & 7;

    if (s < 127) {
      // issue next step's staging into buf[(s+1)%3]; keep it in flight
      const uint4* gsrc = img + (size_t)(s + 1) * 2048 + wave * 64 + lane;
      char* dst = bb + b_nxt * 32768;
      #pragma unroll
      for (int i = 0; i < 4; ++i)
        gload_lds16(gsrc + i * 512, dst + (i * 512 + wave * 64) * 16);
      asm volatile("s_waitcnt vmcnt(4)" ::: "memory");  // step-s loads landed
    } else {
      asm volatile("s_waitcnt vmcnt(0)" ::: "memory");
    }
    __builtin_amdgcn_s_barrier();   // all waves' step-s B in LDS; no drain

    const char* cbuf = bb + b_cur * 32768;

    // acc init: -0.5*||c||^2 (cn is L1-resident, 8 lane-loads per tile)
    if (chunk == 0) {
      #pragma unroll
      for (int cf = 0; cf < 8; ++cf) {
        float h = -cn[tile * 512 + wc * 128 + cf * 16 + l15];
        #pragma unroll
        for (int rf = 0; rf < 4; ++rf) acc[rf][cf] = f32x4{h, h, h, h};
      }
    }

    // fragments
    short8 a[4], b[8];
    #pragma unroll
    for (int rf = 0; rf < 4; ++rf) {
      int m = wgr * 64 + rf * 16 + l15;
      int by = ((chunk * 4 + lgr) ^ (m & 31)) << 4;
      a[rf] = *(const short8*)(zb + m * 512 + by);
    }
    #pragma unroll
    for (int cf = 0; cf < 8; ++cf)
      b[cf] = *(const short8*)(cbuf + (wc * 512 + cf * 64 + lane) * 16);

    #pragma unroll
    for (int rf = 0; rf < 4; ++rf)
      #pragma unroll
      for (int cf = 0; cf < 8; ++cf)
        acc[rf][cf] = __builtin_amdgcn_mfma_f32_16x16x32_bf16(a[rf], b[cf], acc[rf][cf], 0, 0, 0);

    // tile epilogue: fold 8 scores/row-slot into running top-2 (exact ops)
    if (chunk == 7) {
      const int jinvb = 8191 - (tile * 512 + wc * 128 + l15);
      #pragma unroll
      for (int rf = 0; rf < 4; ++rf)
        #pragma unroll
        for (int cf = 0; cf < 8; ++cf) {
          int jinv = jinvb - cf * 16;
          #pragma unroll
          for (int r = 0; r < 4; ++r) {
            int si = rf * 4 + r;
            int iq = (int)(acc[rf][cf][r] * 256.0f);
            int k = iq * 8192 + jinv;
            int t1 = max(k1[si], k);
            int t2 = min(k1[si], k);
            k1[si] = t1;
            k2[si] = max(k2[si], t2);
          }
        }
    }

    b_cur = b_nxt;
    b_nxt = (b_nxt == 2) ? 0 : b_nxt + 1;
  }

  // write candidates: [row][64 buckets] int2
  #pragma unroll
  for (int rf = 0; rf < 4; ++rf)
    #pragma unroll
    for (int r = 0; r < 4; ++r) {
      int row = brow + wgr * 64 + rf * 16 + lgr * 4 + r;
      int si = rf * 4 + r;
      cand[(size_t)row * 64 + wc * 16 + l15] = make_int2(k1[si], k2[si]);
    }
}

// ---------------- K5: exact fp64 refine (top-5) + outputs + loss partials ----
__global__ __launch_bounds__(512)
void k_refine(const float* __restrict__ z, const float* __restrict__ cbTf,
              const int2* __restrict__ cand, float* __restrict__ zq,
              float* __restrict__ oidx, double* __restrict__ parts) {
  __shared__ double lsum[8];
  int lane = threadIdx.x & 63, wave = threadIdx.x >> 6;
  int row = blockIdx.x * 8 + wave;

  float4 z4 = ((const float4*)(z + (size_t)row * DIMS))[lane];
  int2 kp = cand[(size_t)row * 64 + lane];
  int ka = kp.x, kb = kp.y;

  double bd = 1e300; int bj = -1; float4 bc = {0.f, 0.f, 0.f, 0.f};
  for (int s = 0; s < 5; ++s) {
    int km = max(ka, kb);
    #pragma unroll
    for (int m = 1; m < 64; m <<= 1) km = max(km, __shfl_xor(km, m, 64));
    int j = 8191 - (km & 8191);
    if (ka == km) ka = KMIN; else if (kb == km) kb = KMIN;

    float4 c4 = ((const float4*)(cbTf + (size_t)j * DIMS))[lane];
    double dx = (double)z4.x - (double)c4.x;
    double dy = (double)z4.y - (double)c4.y;
    double dzv = (double)z4.z - (double)c4.z;
    double dw = (double)z4.w - (double)c4.w;
    double d = dx * dx + dy * dy + dzv * dzv + dw * dw;
    #pragma unroll
    for (int m = 1; m < 64; m <<= 1) d += __shfl_xor(d, m, 64);

    bool bt = (d < bd) || (d == bd && j < bj);   // wave-uniform
    if (bt) { bd = d; bj = j; bc = c4; }
  }

  ((float4*)(zq + (size_t)row * DIMS))[lane] = bc;
  if (lane == 0) oidx[row] = (float)bj;

  double lx = (double)bc.x - (double)z4.x;
  double ly = (double)bc.y - (double)z4.y;
  double lz = (double)bc.z - (double)z4.z;
  double lw = (double)bc.w - (double)z4.w;
  double l = lx * lx + ly * ly + lz * lz + lw * lw;
  #pragma unroll
  for (int m = 1; m < 64; m <<= 1) l += __shfl_xor(l, m, 64);
  if (lane == 0) lsum[wave] = l;
  __syncthreads();
  if (threadIdx.x == 0) {
    double s = 0;
    for (int i = 0; i < 8; ++i) s += lsum[i];
    parts[blockIdx.x] = s;
  }
}

// ---------------- K6: loss finalize ----------------
__global__ void k_finish(const double* __restrict__ parts, float* __restrict__ out) {
  __shared__ double s[256];
  double a = 0;
  for (int i = threadIdx.x; i < 4096; i += 256) a += parts[i];
  s[threadIdx.x] = a;
  __syncthreads();
  for (int w = 128; w; w >>= 1) {
    if (threadIdx.x < w) s[threadIdx.x] += s[threadIdx.x + w];
    __syncthreads();
  }
  if (threadIdx.x == 0) out[0] = (float)(1.25 * s[0] / 8388608.0);
}

// ---------------- launch ----------------
extern "C" void kernel_launch(void* const* d_in, const int* in_sizes, int n_in,
                              void* d_out, int out_size, void* d_ws, size_t ws_size,
                              hipStream_t stream) {
  const float* zin = (const float*)d_in[0];
  const float* cb  = (const float*)d_in[1];
  float* out = (float*)d_out;

  char* w = (char*)d_ws;
  float*  cn    = (float*)w;                                        // 32 KB
  float*  cbTf  = (float*)(w + 32768);                              // 8 MB
  char*   imgb  = w + 32768 + 8388608;                              // 4 MB (+32KB pad)
  int2*   cand  = (int2*)(w + 32768 + 8388608 + 4194304 + 32768);   // 16 MB
  double* parts = (double*)(w + 32768 + 8388608 + 4194304 + 32768 + 16777216); // 32 KB

  float* zq_out   = out;
  float* idx_out  = out + 8388608;
  float* loss_out = out + 8388608 + 32768;

  k_colnorm<<<dim3(256), dim3(256), 0, stream>>>(cb, cn);
  k_transpose<<<dim3(128, 4), dim3(256), 0, stream>>>(cb, cbTf);
  k_image<<<dim3(1024), dim3(256), 0, stream>>>(cbTf, (uint4*)imgb);
  k_scan<<<dim3(256), dim3(512), 0, stream>>>(zin, cn, (const uint4*)imgb, cand);
  k_refine<<<dim3(4096), dim3(512), 0, stream>>>(zin, cbTf, cand, zq_out, idx_out, parts);
  k_finish<<<dim3(1), dim3(256), 0, stream>>>(parts, loss_out);
}

// Round 9
// 159.431 us; speedup vs baseline: 2.9396x; 1.2909x over previous
//
#include <hip/hip_runtime.h>
#include <hip/hip_bf16.h>
#include <stdint.h>

// VQ-VAE vector quantizer for MI355X (gfx950)
// z: [32768,256] f32, codebook: [256,8192] f32
// out: z_q [8388608] f32, indices-as-f32 [32768], loss [1]
//
// Round 9: round-8 int8 MFMA scan with the SCORE SCALE BUG fixed.
// ẑ = rint(25·z), ĉ = rint(127·c). MFMA dot = ẑ·ĉ = 3175·(z·c).
// Correct integer score:  score = dot − rint((25/254)·||ĉ||²)
//   ∝ z·c − ||c||²/2  (round 8 wrongly used ||ĉ||²/2 → 5.08× norm penalty
//   → all indices biased to small-norm codes). Selection: 64 buckets ×
// top-2 keys ((score>>5)<<13)+jinv, then unchanged exact fp64 top-5 refine.
// LDS: z 32KB (i8, swizzled) | B 3x32KB triple buffer | nrm 32KB = 160KB.

#define DEVINL __device__ __forceinline__

typedef int   intx4 __attribute__((ext_vector_type(4)));

#define NROWS   32768
#define DIMS    256
#define NCODES  8192
#define KMIN    ((int)0x80000000)

// ---------------- helpers ----------------
DEVINL int q8(float v, float s) {
  int q = __float2int_rn(v * s);
  return min(127, max(-127, q));
}
DEVINL unsigned pk4(float4 v, float s) {
  int a = q8(v.x, s), b = q8(v.y, s), c = q8(v.z, s), d = q8(v.w, s);
  return (unsigned)(a & 255) | ((unsigned)(b & 255) << 8) |
         ((unsigned)(c & 255) << 16) | ((unsigned)(d & 255) << 24);
}
DEVINL void gload_lds16(const void* g, void* lds) {
  __builtin_amdgcn_global_load_lds(
      (const __attribute__((address_space(1))) uint32_t*)(uintptr_t)g,
      (__attribute__((address_space(3))) uint32_t*)(uint32_t)(uintptr_t)lds,
      16, 0, 0);
}

// ---------------- K1: scaled norms of quantized codes ----------------
// nrm[j] = rint( (25/254) * sum_d q8(c[d][j]*127)^2 )
//   so that (dot - nrm) == 3175 * (z.c - ||c||^2/2) in quantized units.
__global__ void k_nrm(const float* __restrict__ cb, int* __restrict__ nrm) {
  __shared__ int p[256];
  int j = blockIdx.x * 32 + (threadIdx.x & 31);
  int seg = threadIdx.x >> 5;
  int s = 0;
  for (int i = 0; i < 32; ++i) {
    int q = q8(cb[(size_t)(seg * 32 + i) * NCODES + j], 127.0f);
    s += q * q;
  }
  p[threadIdx.x] = s;
  __syncthreads();
  if (threadIdx.x < 32) {
    int t = 0;
    for (int k = 0; k < 8; ++k) t += p[k * 32 + threadIdx.x];
    nrm[j] = (int)rintf((25.0f / 254.0f) * (float)t);
  }
}

// ---------------- K2: f32 transpose cbTf[j][d] (for exact refine) ----------
__global__ void k_transpose(const float* __restrict__ cb, float* __restrict__ cbTf) {
  __shared__ float t[64][65];
  int j0 = blockIdx.x * 64, d0 = blockIdx.y * 64;
  int tx = threadIdx.x & 63, ty = threadIdx.x >> 6;
  #pragma unroll
  for (int i = 0; i < 16; ++i) {
    int dl = i * 4 + ty;
    t[dl][tx] = cb[(size_t)(d0 + dl) * NCODES + j0 + tx];
  }
  __syncthreads();
  #pragma unroll
  for (int i = 0; i < 16; ++i) {
    int jl = i * 4 + ty;
    cbTf[(size_t)(j0 + jl) * DIMS + d0 + tx] = t[tx][jl];
  }
}

// ---------------- K3: i8 fragment image ----------------
// granule g (16B = 16 K-bytes) = [step 64][wc 4][cf 8][lgr 4][l15 16]
//   step = tile*4+chunk; code j = tile*512 + wc*128 + cf*16 + l15
//   dims d = chunk*64 + lgr*16 .. +16  (linear K within granule)
__global__ void k_image(const float* __restrict__ cbTf, uint4* __restrict__ img) {
  int g = blockIdx.x * 256 + threadIdx.x;     // 0..131071
  int step = g >> 11;                          // 0..63
  int r = g & 2047;
  int wc = r >> 9, cf = (r >> 6) & 7, lgr = (r >> 4) & 3, l15 = r & 15;
  int tile = step >> 2, chunk = step & 3;
  int j = tile * 512 + wc * 128 + cf * 16 + l15;
  int d = chunk * 64 + lgr * 16;
  const float4* s4 = (const float4*)(cbTf + (size_t)j * DIMS + d);
  uint4 o;
  o.x = pk4(s4[0], 127.0f); o.y = pk4(s4[1], 127.0f);
  o.z = pk4(s4[2], 127.0f); o.w = pk4(s4[3], 127.0f);
  img[g] = o;
}

// ---------------- K4: i8 MFMA scan, counted-vmcnt triple buffer ------------
// 256 blocks x 512 threads. Block: 128 rows x 8192 codes, 64 steps of K=64.
// Waves: wgr(2) x wc(4); wave-tile 64 rows x 128 codes; 16x16x64 rf4 x cf8.
__global__ __launch_bounds__(512, 2)
void k_scan(const float* __restrict__ z, const int* __restrict__ nrm,
            const uint4* __restrict__ img, int2* __restrict__ cand) {
  __shared__ char smem[163840];
  char* const zb = smem;                        // 32 KB: 128 rows x 256 i8
  char* const bb = smem + 32768;                // 3 x 32 KB B buffers
  const int* const nl = (const int*)(smem + 131072);  // 32 KB nrm

  const int t = threadIdx.x;
  const int lane = t & 63;
  const int wave = t >> 6;
  const int wgr = wave >> 2;
  const int wc  = wave & 3;
  const int l15 = lane & 15;
  const int lgr = lane >> 4;
  const int brow = blockIdx.x * 128;

  // stage z: 2048 granules (16 K-bytes each); pos = (kblk*16)^((row&15)<<4)
  #pragma unroll
  for (int i = 0; i < 4; ++i) {
    int g = t + i * 512;
    int row = g >> 4, kb = g & 15;
    const float4* src = (const float4*)(z + (size_t)(brow + row) * DIMS + kb * 16);
    uint4 o;
    o.x = pk4(src[0], 25.0f); o.y = pk4(src[1], 25.0f);
    o.z = pk4(src[2], 25.0f); o.w = pk4(src[3], 25.0f);
    int addr = row * 256 + ((kb * 16) ^ ((row & 15) << 4));
    *(uint4*)(zb + addr) = o;
  }
  // stage nrm: 2048 x 16B, linear
  #pragma unroll
  for (int i = 0; i < 4; ++i) {
    int gi = t + i * 512;
    ((uint4*)(smem + 131072))[gi] = ((const uint4*)nrm)[gi];
  }
  // stage B step 0 into buf0 (wave-uniform base; lanes scatter by 16B)
  {
    const uint4* gsrc = img + wave * 64 + lane;
    #pragma unroll
    for (int i = 0; i < 4; ++i)
      gload_lds16(gsrc + i * 512, bb + (i * 512 + wave * 64) * 16);
  }

  // per row-slot top-2 packed keys
  int k1[16], k2[16];
  #pragma unroll
  for (int i = 0; i < 16; ++i) { k1[i] = KMIN; k2[i] = KMIN; }

  __syncthreads();   // z/nrm visible; step-0 B resident

  intx4 acc[4][8];
  int b_cur = 0, b_nxt = 1;

  #pragma unroll 1
  for (int s = 0; s < 64; ++s) {
    const int tile = s >> 2, chunk = s & 3;

    if (s < 63) {
      const uint4* gsrc = img + (size_t)(s + 1) * 2048 + wave * 64 + lane;
      char* dst = bb + b_nxt * 32768;
      #pragma unroll
      for (int i = 0; i < 4; ++i)
        gload_lds16(gsrc + i * 512, dst + (i * 512 + wave * 64) * 16);
      asm volatile("s_waitcnt vmcnt(4)" ::: "memory");
    } else {
      asm volatile("s_waitcnt vmcnt(0)" ::: "memory");
    }
    __builtin_amdgcn_s_barrier();

    const char* cbuf = bb + b_cur * 32768;

    // acc init: -nrm (scaled norm) from LDS
    if (chunk == 0) {
      #pragma unroll
      for (int cf = 0; cf < 8; ++cf) {
        int h = -nl[tile * 512 + wc * 128 + cf * 16 + l15];
        #pragma unroll
        for (int rf = 0; rf < 4; ++rf) acc[rf][cf] = intx4{h, h, h, h};
      }
    }

    // fragments
    intx4 a[4], b[8];
    #pragma unroll
    for (int rf = 0; rf < 4; ++rf) {
      int m = wgr * 64 + rf * 16 + l15;
      int by = (chunk * 64 + lgr * 16) ^ ((m & 15) << 4);
      a[rf] = *(const intx4*)(zb + m * 256 + by);
    }
    #pragma unroll
    for (int cf = 0; cf < 8; ++cf)
      b[cf] = *(const intx4*)(cbuf + (wc * 512 + cf * 64 + lane) * 16);

    #pragma unroll
    for (int rf = 0; rf < 4; ++rf)
      #pragma unroll
      for (int cf = 0; cf < 8; ++cf)
        acc[rf][cf] = __builtin_amdgcn_mfma_i32_16x16x64_i8(a[rf], b[cf], acc[rf][cf], 0, 0, 0);

    // tile epilogue: fold 8 int scores/row-slot into running top-2
    if (chunk == 3) {
      const int jinvb = 8191 - (tile * 512 + wc * 128 + l15);
      #pragma unroll
      for (int rf = 0; rf < 4; ++rf)
        #pragma unroll
        for (int cf = 0; cf < 8; ++cf) {
          int jinv = jinvb - cf * 16;
          #pragma unroll
          for (int r = 0; r < 4; ++r) {
            int si = rf * 4 + r;
            int k = ((acc[rf][cf][r] >> 5) << 13) + jinv;
            int t1 = max(k1[si], k);
            int t2 = min(k1[si], k);
            k1[si] = t1;
            k2[si] = max(k2[si], t2);
          }
        }
    }

    b_cur = b_nxt;
    b_nxt = (b_nxt == 2) ? 0 : b_nxt + 1;
  }

  // write candidates: [row][64 buckets] int2
  #pragma unroll
  for (int rf = 0; rf < 4; ++rf)
    #pragma unroll
    for (int r = 0; r < 4; ++r) {
      int row = brow + wgr * 64 + rf * 16 + lgr * 4 + r;
      int si = rf * 4 + r;
      cand[(size_t)row * 64 + wc * 16 + l15] = make_int2(k1[si], k2[si]);
    }
}

// ---------------- K5: exact fp64 refine (top-5) + outputs + loss partials ----
__global__ __launch_bounds__(512)
void k_refine(const float* __restrict__ z, const float* __restrict__ cbTf,
              const int2* __restrict__ cand, float* __restrict__ zq,
              float* __restrict__ oidx, double* __restrict__ parts) {
  __shared__ double lsum[8];
  int lane = threadIdx.x & 63, wave = threadIdx.x >> 6;
  int row = blockIdx.x * 8 + wave;

  float4 z4 = ((const float4*)(z + (size_t)row * DIMS))[lane];
  int2 kp = cand[(size_t)row * 64 + lane];
  int ka = kp.x, kb = kp.y;

  double bd = 1e300; int bj = -1; float4 bc = {0.f, 0.f, 0.f, 0.f};
  for (int s = 0; s < 5; ++s) {
    int km = max(ka, kb);
    #pragma unroll
    for (int m = 1; m < 64; m <<= 1) km = max(km, __shfl_xor(km, m, 64));
    int j = 8191 - (km & 8191);
    if (ka == km) ka = KMIN; else if (kb == km) kb = KMIN;

    float4 c4 = ((const float4*)(cbTf + (size_t)j * DIMS))[lane];
    double dx = (double)z4.x - (double)c4.x;
    double dy = (double)z4.y - (double)c4.y;
    double dzv = (double)z4.z - (double)c4.z;
    double dw = (double)z4.w - (double)c4.w;
    double d = dx * dx + dy * dy + dzv * dzv + dw * dw;
    #pragma unroll
    for (int m = 1; m < 64; m <<= 1) d += __shfl_xor(d, m, 64);

    bool bt = (d < bd) || (d == bd && j < bj);   // wave-uniform
    if (bt) { bd = d; bj = j; bc = c4; }
  }

  ((float4*)(zq + (size_t)row * DIMS))[lane] = bc;
  if (lane == 0) oidx[row] = (float)bj;

  double lx = (double)bc.x - (double)z4.x;
  double ly = (double)bc.y - (double)z4.y;
  double lz = (double)bc.z - (double)z4.z;
  double lw = (double)bc.w - (double)z4.w;
  double l = lx * lx + ly * ly + lz * lz + lw * lw;
  #pragma unroll
  for (int m = 1; m < 64; m <<= 1) l += __shfl_xor(l, m, 64);
  if (lane == 0) lsum[wave] = l;
  __syncthreads();
  if (threadIdx.x == 0) {
    double s = 0;
    for (int i = 0; i < 8; ++i) s += lsum[i];
    parts[blockIdx.x] = s;
  }
}

// ---------------- K6: loss finalize ----------------
__global__ void k_finish(const double* __restrict__ parts, float* __restrict__ out) {
  __shared__ double s[256];
  double a = 0;
  for (int i = threadIdx.x; i < 4096; i += 256) a += parts[i];
  s[threadIdx.x] = a;
  __syncthreads();
  for (int w = 128; w; w >>= 1) {
    if (threadIdx.x < w) s[threadIdx.x] += s[threadIdx.x + w];
    __syncthreads();
  }
  if (threadIdx.x == 0) out[0] = (float)(1.25 * s[0] / 8388608.0);
}

// ---------------- launch ----------------
extern "C" void kernel_launch(void* const* d_in, const int* in_sizes, int n_in,
                              void* d_out, int out_size, void* d_ws, size_t ws_size,
                              hipStream_t stream) {
  const float* zin = (const float*)d_in[0];
  const float* cb  = (const float*)d_in[1];
  float* out = (float*)d_out;

  char* w = (char*)d_ws;
  int*    nrm   = (int*)w;                                          // 32 KB
  float*  cbTf  = (float*)(w + 32768);                              // 8 MB
  char*   imgb  = w + 32768 + 8388608;                              // 2 MB
  int2*   cand  = (int2*)(w + 32768 + 8388608 + 2097152);           // 16 MB
  double* parts = (double*)(w + 32768 + 8388608 + 2097152 + 16777216); // 32 KB

  float* zq_out   = out;
  float* idx_out  = out + 8388608;
  float* loss_out = out + 8388608 + 32768;

  k_nrm<<<dim3(256), dim3(256), 0, stream>>>(cb, nrm);
  k_transpose<<<dim3(128, 4), dim3(256), 0, stream>>>(cb, cbTf);
  k_image<<<dim3(512), dim3(256), 0, stream>>>(cbTf, (uint4*)imgb);
  k_scan<<<dim3(256), dim3(512), 0, stream>>>(zin, nrm, (const uint4*)imgb, cand);
  k_refine<<<dim3(4096), dim3(512), 0, stream>>>(zin, cbTf, cand, zq_out, idx_out, parts);
  k_finish<<<dim3(1), dim3(256), 0, stream>>>(parts, loss_out);
}